// Round 2
// baseline (95.672 us; speedup 1.0000x reference)
//
#include <hip/hip_runtime.h>
#include <hip/hip_bf16.h>

#define B_   4
#define M_   1024
#define N_   1024
#define P_   2048
#define D_   512
#define TILE 128
#define BK   32
#define TT   (P_/TILE)        /* 16 tile-rows */
#define NTRI (TT*(TT+1)/2)    /* 136 upper-triangular tiles */

typedef __bf16 bf16x8 __attribute__((ext_vector_type(8)));
typedef float  f32x4  __attribute__((ext_vector_type(4)));

__device__ __forceinline__ void glds16(const void* g, void* l) {
    __builtin_amdgcn_global_load_lds(
        (const __attribute__((address_space(1))) void*)g,
        (__attribute__((address_space(3))) void*)l, 16, 0, 0);
}

// Kernel 1: z -> bf16 (workspace), z2[row] = -0.5*sum(round(z)^2), wc = [w_in, -w_tar].
// Also zeroes ksum[0..3] (d_ws is poisoned 0xAA before every launch).
__global__ void __launch_bounds__(256)
prep_kernel(const float* __restrict__ in, const float* __restrict__ tar,
            const float* __restrict__ w_in, const float* __restrict__ w_tar,
            __hip_bfloat16* __restrict__ zb, float* __restrict__ z2,
            float* __restrict__ wc, float* __restrict__ ksum)
{
    const int row = blockIdx.x;            // 0 .. B*P-1
    const int b = row >> 11;               // /P_
    const int p = row & (P_ - 1);
    const float* src = (p < M_) ? (in  + ((size_t)b*M_ + p)        * D_)
                                : (tar + ((size_t)b*N_ + (p - M_)) * D_);
    const int t = threadIdx.x;
    __hip_bfloat16* dst = zb + (size_t)row * D_;
    float s = 0.f;
    for (int i = t; i < D_; i += 256) {
        float x = src[i];
        __hip_bfloat16 h = __float2bfloat16(x);
        dst[i] = h;
        float xr = __bfloat162float(h);     // square the ROUNDED value (diag consistency)
        s = fmaf(xr, xr, s);
    }
    #pragma unroll
    for (int off = 32; off; off >>= 1) s += __shfl_down(s, off, 64);
    __shared__ float red[4];
    if ((t & 63) == 0) red[t >> 6] = s;
    __syncthreads();
    if (t == 0) {
        z2[row] = -0.5f * (red[0] + red[1] + red[2] + red[3]);
        wc[row] = (p < M_) ? w_in[(size_t)b*M_ + p] : -w_tar[(size_t)b*N_ + (p - M_)];
        if (row < B_) ksum[row] = 0.f;
    }
}

// Kernel 2: fused Gram-GEMM + exp epilogue. Upper-triangular 128x128 tiles,
// off-diagonal tiles contribute 2x by symmetry.
__global__ void __launch_bounds__(256)
mmd_kernel(const __hip_bfloat16* __restrict__ zb, const float* __restrict__ z2,
           const float* __restrict__ wc, float* __restrict__ ksum)
{
    __shared__ __align__(16) __bf16 As[TILE*BK];
    __shared__ __align__(16) __bf16 Bs[TILE*BK];
    __shared__ float z2p[TILE], z2q[TILE], wp[TILE], wq[TILE];
    __shared__ float red[4];

    const int b = blockIdx.y;
    int pt = 0, rem = blockIdx.x;
    while (rem >= TT - pt) { rem -= TT - pt; ++pt; }
    const int qt = pt + rem;

    const int tid  = threadIdx.x;
    const int lane = tid & 63;
    const int w    = tid >> 6;
    const int wm   = w & 1;     // wave tile row (x64)
    const int wn   = w >> 1;    // wave tile col (x64)

    if (tid < TILE) {
        z2p[tid] = z2[(size_t)b*P_ + pt*TILE + tid];
        wp[tid]  = wc[(size_t)b*P_ + pt*TILE + tid];
    } else {
        int i = tid - TILE;
        z2q[i] = z2[(size_t)b*P_ + qt*TILE + i];
        wq[i]  = wc[(size_t)b*P_ + qt*TILE + i];
    }

    const __hip_bfloat16* zA = zb + ((size_t)b*P_ + pt*TILE) * D_;
    const __hip_bfloat16* zB = zb + ((size_t)b*P_ + qt*TILE) * D_;

    f32x4 acc[4][4];
    const f32x4 zero = {0.f, 0.f, 0.f, 0.f};
    #pragma unroll
    for (int mi = 0; mi < 4; ++mi)
        #pragma unroll
        for (int ni = 0; ni < 4; ++ni) acc[mi][ni] = zero;

    const int m  = lane & 15;       // A/B fragment row
    const int kq = lane >> 4;       // k-quad
    const int rA = lane >> 2;       // staging: row within 16-row segment
    const int cA = (lane & 3) * 8;  // staging: k offset (8 bf16 = 16 B)

    for (int k0 = 0; k0 < D_; k0 += BK) {
        #pragma unroll
        for (int j = 0; j < 2; ++j) {
            const int rseg = (w*2 + j) * 16;
            glds16(zA + (size_t)(rseg + rA)*D_ + k0 + cA, &As[rseg*BK]);
            glds16(zB + (size_t)(rseg + rA)*D_ + k0 + cA, &Bs[rseg*BK]);
        }
        __syncthreads();

        bf16x8 af[4], bfv[4];
        #pragma unroll
        for (int mi = 0; mi < 4; ++mi)
            af[mi] = *(const bf16x8*)&As[(wm*64 + mi*16 + m)*BK + kq*8];
        #pragma unroll
        for (int ni = 0; ni < 4; ++ni)
            bfv[ni] = *(const bf16x8*)&Bs[(wn*64 + ni*16 + m)*BK + kq*8];

        #pragma unroll
        for (int mi = 0; mi < 4; ++mi)
            #pragma unroll
            for (int ni = 0; ni < 4; ++ni)
                acc[mi][ni] = __builtin_amdgcn_mfma_f32_16x16x32_bf16(
                    af[mi], bfv[ni], acc[mi][ni], 0, 0, 0);
        __syncthreads();
    }

    // Epilogue: e = dot + z2p + z2q; t = exp(e/8); sum over sigmas = t+t^2+t^4+t^8
    const float K8 = 0.18033688011112042f;   // log2(e)/8
    float part = 0.f;
    #pragma unroll
    for (int mi = 0; mi < 4; ++mi) {
        const int pl0 = wm*64 + mi*16 + kq*4;  // C row = (lane>>4)*4 + reg
        #pragma unroll
        for (int ni = 0; ni < 4; ++ni) {
            const int ql = wn*64 + ni*16 + m;  // C col = lane&15
            const float zq  = z2q[ql];
            const float wqv = wq[ql];
            #pragma unroll
            for (int r = 0; r < 4; ++r) {
                float e  = acc[mi][ni][r] + z2p[pl0 + r] + zq;
                float tt = exp2f(e * K8);
                float t2 = tt*tt, t4 = t2*t2, t8 = t4*t4;
                part += wp[pl0 + r] * wqv * (tt + t2 + t4 + t8);
            }
        }
    }
    #pragma unroll
    for (int off = 32; off; off >>= 1) part += __shfl_down(part, off, 64);
    if (lane == 0) red[w] = part;
    __syncthreads();
    if (tid == 0) {
        float tot = red[0] + red[1] + red[2] + red[3];
        if (pt != qt) tot *= 2.f;      // symmetric counterpart tile not computed
        atomicAdd(&ksum[b], tot);
    }
}

__global__ void finalize_kernel(const float* __restrict__ ksum, float* __restrict__ out)
{
    if (threadIdx.x == 0 && blockIdx.x == 0) {
        float s = 0.f;
        for (int b = 0; b < B_; ++b) s += sqrtf(ksum[b] + 1e-4f);
        out[0] = s;
    }
}

extern "C" void kernel_launch(void* const* d_in, const int* in_sizes, int n_in,
                              void* d_out, int out_size, void* d_ws, size_t ws_size,
                              hipStream_t stream)
{
    const float* input  = (const float*)d_in[0];
    const float* target = (const float*)d_in[1];
    const float* w_in   = (const float*)d_in[2];
    const float* w_tar  = (const float*)d_in[3];

    char* ws = (char*)d_ws;
    __hip_bfloat16* zb = (__hip_bfloat16*)ws;                 // B*P*D bf16 = 8 MiB
    const size_t zb_bytes = (size_t)B_ * P_ * D_ * sizeof(__hip_bfloat16);
    float* z2   = (float*)(ws + zb_bytes);                    // B*P
    float* wc   = z2 + (size_t)B_ * P_;                       // B*P
    float* ksum = wc + (size_t)B_ * P_;                       // B_ floats
    float* out  = (float*)d_out;

    hipLaunchKernelGGL(prep_kernel, dim3(B_*P_), dim3(256), 0, stream,
                       input, target, w_in, w_tar, zb, z2, wc, ksum);
    hipLaunchKernelGGL(mmd_kernel, dim3(NTRI, B_), dim3(256), 0, stream,
                       zb, z2, wc, ksum);
    hipLaunchKernelGGL(finalize_kernel, dim3(1), dim3(64), 0, stream, ksum, out);
}

// Round 3
// 91.191 us; speedup vs baseline: 1.0491x; 1.0491x over previous
//
#include <hip/hip_runtime.h>
#include <hip/hip_bf16.h>

#define B_   4
#define M_   1024
#define N_   1024
#define P_   2048
#define D_   512
#define TILE 128
#define BK   32
#define TT   (P_/TILE)        /* 16 tile-rows */
#define NTRI (TT*(TT+1)/2)    /* 136 upper-triangular tiles */

typedef __bf16 bf16x8 __attribute__((ext_vector_type(8)));
typedef float  f32x4  __attribute__((ext_vector_type(4)));
typedef float  f32x8  __attribute__((ext_vector_type(8)));
typedef unsigned short u16x8 __attribute__((ext_vector_type(8)));

__device__ __forceinline__ void glds16(const void* g, void* l) {
    __builtin_amdgcn_global_load_lds(
        (const __attribute__((address_space(1))) void*)g,
        (__attribute__((address_space(3))) void*)l, 16, 0, 0);
}

// Kernel 1: z -> bf16 (workspace), z2[row] = -0.5*sum(round(z)^2), wc = [w_in, -w_tar].
// One wave per row: 64 lanes x 8 floats = 512 = D. Also zeroes ksum[0..3].
__global__ void __launch_bounds__(256)
prep_kernel(const float* __restrict__ in, const float* __restrict__ tar,
            const float* __restrict__ w_in, const float* __restrict__ w_tar,
            __hip_bfloat16* __restrict__ zb, float* __restrict__ z2,
            float* __restrict__ wc, float* __restrict__ ksum)
{
    const int wv   = threadIdx.x >> 6;
    const int lane = threadIdx.x & 63;
    const int row  = blockIdx.x * 4 + wv;   // 0 .. B*P-1 (grid 2048)
    const int b = row >> 11;                // /P_
    const int p = row & (P_ - 1);
    const float* src = (p < M_) ? (in  + ((size_t)b*M_ + p)        * D_)
                                : (tar + ((size_t)b*N_ + (p - M_)) * D_);
    f32x8 v = ((const f32x8*)src)[lane];    // 32 B/lane, coalesced
    u16x8 ob;
    float s = 0.f;
    #pragma unroll
    for (int j = 0; j < 8; ++j) {
        __hip_bfloat16 h = __float2bfloat16(v[j]);
        union { __hip_bfloat16 h; unsigned short u; } cv; cv.h = h;
        ob[j] = cv.u;
        float xr = __bfloat162float(h);     // square the ROUNDED value (diag consistency)
        s = fmaf(xr, xr, s);
    }
    ((u16x8*)(zb + (size_t)row * D_))[lane] = ob;
    #pragma unroll
    for (int off = 32; off; off >>= 1) s += __shfl_down(s, off, 64);
    if (lane == 0) {
        z2[row] = -0.5f * s;
        wc[row] = (p < M_) ? w_in[(size_t)b*M_ + p] : -w_tar[(size_t)b*N_ + (p - M_)];
    }
    if (blockIdx.x == 0 && wv == 0 && lane < B_) ksum[lane] = 0.f;
}

// Kernel 2: fused Gram-GEMM + exp epilogue. Upper-triangular 128x128 tiles,
// off-diagonal tiles contribute 2x by symmetry.
// LDS layout XOR-swizzled: row r, chunk position c (16 B) holds global k-chunk
// c ^ ((r>>1)&3)  -> fragment reads hit 8 bank-groups x 2 lanes = conflict-free.
__global__ void __launch_bounds__(256)
mmd_kernel(const __hip_bfloat16* __restrict__ zb, const float* __restrict__ z2,
           const float* __restrict__ wc, float* __restrict__ ksum)
{
    __shared__ __align__(16) __bf16 As[TILE*BK];
    __shared__ __align__(16) __bf16 Bs[TILE*BK];
    __shared__ float z2p[TILE], z2q[TILE], wp[TILE], wq[TILE];
    __shared__ float red[4];

    const int b = blockIdx.y;
    int pt = 0, rem = blockIdx.x;
    while (rem >= TT - pt) { rem -= TT - pt; ++pt; }
    const int qt = pt + rem;

    const int tid  = threadIdx.x;
    const int lane = tid & 63;
    const int w    = tid >> 6;
    const int wm   = w & 1;     // wave tile row (x64)
    const int wn   = w >> 1;    // wave tile col (x64)

    if (tid < TILE) {
        z2p[tid] = z2[(size_t)b*P_ + pt*TILE + tid];
        wp[tid]  = wc[(size_t)b*P_ + pt*TILE + tid];
    } else {
        int i = tid - TILE;
        z2q[i] = z2[(size_t)b*P_ + qt*TILE + i];
        wq[i]  = wc[(size_t)b*P_ + qt*TILE + i];
    }

    const __hip_bfloat16* zA = zb + ((size_t)b*P_ + pt*TILE) * D_;
    const __hip_bfloat16* zB = zb + ((size_t)b*P_ + qt*TILE) * D_;

    f32x4 acc[4][4];
    const f32x4 zero = {0.f, 0.f, 0.f, 0.f};
    #pragma unroll
    for (int mi = 0; mi < 4; ++mi)
        #pragma unroll
        for (int ni = 0; ni < 4; ++ni) acc[mi][ni] = zero;

    const int m  = lane & 15;       // A/B fragment row
    const int kq = lane >> 4;       // k-quad
    const int rA = lane >> 2;       // staging: row within 16-row segment
    // staging source k-chunk, XOR-swizzled vs the fixed lane-contiguous LDS dest:
    const int cA = (((lane & 3) ^ ((lane >> 3) & 3)) * 8);
    // fragment read chunk position:
    const int pos = (kq ^ ((m >> 1) & 3)) * 8;

    for (int k0 = 0; k0 < D_; k0 += BK) {
        #pragma unroll
        for (int j = 0; j < 2; ++j) {
            const int rseg = (w*2 + j) * 16;
            glds16(zA + (size_t)(rseg + rA)*D_ + k0 + cA, &As[rseg*BK]);
            glds16(zB + (size_t)(rseg + rA)*D_ + k0 + cA, &Bs[rseg*BK]);
        }
        __syncthreads();

        bf16x8 af[4], bfv[4];
        #pragma unroll
        for (int mi = 0; mi < 4; ++mi)
            af[mi] = *(const bf16x8*)&As[(wm*64 + mi*16 + m)*BK + pos];
        #pragma unroll
        for (int ni = 0; ni < 4; ++ni)
            bfv[ni] = *(const bf16x8*)&Bs[(wn*64 + ni*16 + m)*BK + pos];

        #pragma unroll
        for (int mi = 0; mi < 4; ++mi)
            #pragma unroll
            for (int ni = 0; ni < 4; ++ni)
                acc[mi][ni] = __builtin_amdgcn_mfma_f32_16x16x32_bf16(
                    af[mi], bfv[ni], acc[mi][ni], 0, 0, 0);
        __syncthreads();
    }

    // Epilogue: e = dot + z2p + z2q; t = exp(e/8); sum over sigmas = t+t^2+t^4+t^8
    const float K8 = 0.18033688011112042f;   // log2(e)/8
    float part = 0.f;
    #pragma unroll
    for (int mi = 0; mi < 4; ++mi) {
        const int pl0 = wm*64 + mi*16 + kq*4;  // C row = (lane>>4)*4 + reg
        #pragma unroll
        for (int ni = 0; ni < 4; ++ni) {
            const int ql = wn*64 + ni*16 + m;  // C col = lane&15
            const float zq  = z2q[ql];
            const float wqv = wq[ql];
            #pragma unroll
            for (int r = 0; r < 4; ++r) {
                float e  = acc[mi][ni][r] + z2p[pl0 + r] + zq;
                float tt = exp2f(e * K8);
                float t2 = tt*tt, t4 = t2*t2, t8 = t4*t4;
                part += wp[pl0 + r] * wqv * (tt + t2 + t4 + t8);
            }
        }
    }
    #pragma unroll
    for (int off = 32; off; off >>= 1) part += __shfl_down(part, off, 64);
    if (lane == 0) red[w] = part;
    __syncthreads();
    if (tid == 0) {
        float tot = red[0] + red[1] + red[2] + red[3];
        if (pt != qt) tot *= 2.f;      // symmetric counterpart tile not computed
        atomicAdd(&ksum[b], tot);
    }
}

__global__ void finalize_kernel(const float* __restrict__ ksum, float* __restrict__ out)
{
    if (threadIdx.x == 0 && blockIdx.x == 0) {
        float s = 0.f;
        for (int b = 0; b < B_; ++b) s += sqrtf(ksum[b] + 1e-4f);
        out[0] = s;
    }
}

extern "C" void kernel_launch(void* const* d_in, const int* in_sizes, int n_in,
                              void* d_out, int out_size, void* d_ws, size_t ws_size,
                              hipStream_t stream)
{
    const float* input  = (const float*)d_in[0];
    const float* target = (const float*)d_in[1];
    const float* w_in   = (const float*)d_in[2];
    const float* w_tar  = (const float*)d_in[3];

    char* ws = (char*)d_ws;
    __hip_bfloat16* zb = (__hip_bfloat16*)ws;                 // B*P*D bf16 = 8 MiB
    const size_t zb_bytes = (size_t)B_ * P_ * D_ * sizeof(__hip_bfloat16);
    float* z2   = (float*)(ws + zb_bytes);                    // B*P
    float* wc   = z2 + (size_t)B_ * P_;                       // B*P
    float* ksum = wc + (size_t)B_ * P_;                       // B_ floats
    float* out  = (float*)d_out;

    hipLaunchKernelGGL(prep_kernel, dim3(B_*P_/4), dim3(256), 0, stream,
                       input, target, w_in, w_tar, zb, z2, wc, ksum);
    hipLaunchKernelGGL(mmd_kernel, dim3(NTRI, B_), dim3(256), 0, stream,
                       zb, z2, wc, ksum);
    hipLaunchKernelGGL(finalize_kernel, dim3(1), dim3(64), 0, stream, ksum, out);
}